// Round 3
// baseline (72.985 us; speedup 1.0000x reference)
//
#include <hip/hip_runtime.h>
#include <math.h>
#include <limits.h>

#define NUM_CLS   80
#define MAX_BOXES 128
#define NLVL      5
#define TOTAL_PIX 34100

#define CLS_F4    699050   // 34100*82/4
#define REG_F4    51150    // 34100*6/4
#define KEY_U4    17050    // 34100*8/16

// ---------------- kernel 1: defaults + key init (fully coalesced) ----------
__global__ __launch_bounds__(256) void init_kernel(
    float* __restrict__ out_cls, float* __restrict__ out_reg,
    unsigned long long* __restrict__ keys)
{
    const int tid = blockIdx.x * 256 + threadIdx.x;
    const int nth = gridDim.x * 256;

    // cls default row: 82 floats, all 0 except col 80 (soft) = 1
    float4* cp = (float4*)out_cls;
    for (int q = tid; q < CLS_F4; q += nth) {
        const int flat = q * 4;
        const int c0 = flat - ((int)((unsigned)flat / 82u)) * 82;
        // c0+k in [0,84]; wrapped cols (>=82) map to 0..2, never 80 -> direct compare ok
        float4 v;
        v.x = (c0     == 80) ? 1.f : 0.f;
        v.y = (c0 + 1 == 80) ? 1.f : 0.f;
        v.z = (c0 + 2 == 80) ? 1.f : 0.f;
        v.w = (c0 + 3 == 80) ? 1.f : 0.f;
        cp[q] = v;
    }
    // regr default row: 6 floats, all 0 except col 4 (soft) = 1
    float4* rp = (float4*)out_reg;
    for (int q = tid; q < REG_F4; q += nth) {
        const int flat = q * 4;
        const int c0 = flat - ((int)((unsigned)flat / 6u)) * 6;
        // c0+k in [0,8]; wrapped cols map to 0..2, never 4 -> direct compare ok
        float4 v;
        v.x = (c0     == 4) ? 1.f : 0.f;
        v.y = (c0 + 1 == 4) ? 1.f : 0.f;
        v.z = (c0 + 2 == 4) ? 1.f : 0.f;
        v.w = (c0 + 3 == 4) ? 1.f : 0.f;
        rp[q] = v;
    }
    // keys = UINT64_MAX
    uint4* kp = (uint4*)keys;
    const uint4 ff = make_uint4(~0u, ~0u, ~0u, ~0u);
    for (int q = tid; q < KEY_U4; q += nth) kp[q] = ff;
}

// ---------------- kernel 2: rasterize shrunk rects, atomicMin claims -------
__global__ __launch_bounds__(256) void scatter_kernel(
    const float* __restrict__ gt,
    unsigned long long* __restrict__ keys)
{
    const int t = blockIdx.x * 256 + threadIdx.x;
    if (t >= MAX_BOXES * NLVL) return;
    const int box = t / NLVL;
    const int lvl = t - box * NLVL;      // interleave levels for balance

    const float x1 = gt[box * 5 + 0];
    const float y1 = gt[box * 5 + 1];
    const float x2 = gt[box * 5 + 2];
    const float y2 = gt[box * 5 + 3];
    const bool valid = (fabsf(x1) > 0.f) || (fabsf(y1) > 0.f) ||
                       (fabsf(x2) > 0.f) || (fabsf(y2) > 0.f);
    if (!valid) return;

    const float stride = (float)(8 << lvl);
    const float inv_s  = 1.0f / stride;          // exact pow2
    const int   fw     = 160 >> lvl;
    const float fwm1   = (float)(fw - 1);
    const int   base   = (lvl == 0) ? 0 : (lvl == 1) ? 25600 :
                         (lvl == 2) ? 32000 : (lvl == 3) ? 33600 : 34000;

    // shrink box, op order matching reference exactly
    const float bx1 = x1 * inv_s, by1 = y1 * inv_s;
    const float bx2 = x2 * inv_s, by2 = y2 * inv_s;
    const float cx = (bx1 + bx2) * 0.5f;
    const float cy = (by1 + by2) * 0.5f;
    const float hw = ((bx2 - bx1) * 0.2f) * 0.5f;
    const float hh = ((by2 - by1) * 0.2f) * 0.5f;
    const int px1 = (int)fminf(fmaxf(floorf(cx - hw), 0.f), fwm1);
    const int py1 = (int)fminf(fmaxf(floorf(cy - hh), 0.f), fwm1);
    const int px2 = min(max((int)ceilf(cx + hw), px1 + 1), fw);
    const int py2 = min(max((int)ceilf(cy + hh), py1 + 1), fw);

    for (int gy = py1; gy < py2; ++gy) {
        const float sy = ((float)gy + 0.5f) * stride;
        const float dt = fmaxf(sy - y1, 0.f);
        const float db = fmaxf(y2 - sy, 0.f);
        const float vsum = dt + db;
        for (int gx = px1; gx < px2; ++gx) {
            const float sx = ((float)gx + 0.5f) * stride;
            const float dl = fmaxf(sx - x1, 0.f);
            const float dr = fmaxf(x2 - sx, 0.f);
            const float area = (dl + dr) * vsum;   // identical to ref formula
            const unsigned long long key =
                ((unsigned long long)__float_as_uint(area) << 32) |
                (unsigned long long)(unsigned)box;
            atomicMin(&keys[base + gy * fw + gx], key);
        }
    }
}

// ---------------- kernel 3: rewrite claimed pixels -------------------------
__global__ __launch_bounds__(256) void finalize_kernel(
    const float* __restrict__ gt, const float* __restrict__ fsw,
    const unsigned long long* __restrict__ keys,
    float* __restrict__ out_cls, float* __restrict__ out_reg)
{
    const int pid = blockIdx.x * 256 + threadIdx.x;
    if (pid >= TOTAL_PIX) return;
    const unsigned long long k = keys[pid];
    if (k == ~0ull) return;                     // no winner: defaults stand

    const int win = (int)(unsigned)(k & 0xffffffffu);

    int lvl, fw, lp;
    float stride;
    if      (pid < 25600) { lvl = 0; fw = 160; lp = pid;         stride = 8.f;   }
    else if (pid < 32000) { lvl = 1; fw = 80;  lp = pid - 25600; stride = 16.f;  }
    else if (pid < 33600) { lvl = 2; fw = 40;  lp = pid - 32000; stride = 32.f;  }
    else if (pid < 34000) { lvl = 3; fw = 20;  lp = pid - 33600; stride = 64.f;  }
    else                  { lvl = 4; fw = 10;  lp = pid - 34000; stride = 128.f; }
    const int gy = lp / fw;
    const int gx = lp - gy * fw;
    const float sx = ((float)gx + 0.5f) * stride;
    const float sy = ((float)gy + 0.5f) * stride;

    const float x1 = gt[win * 5 + 0];
    const float y1 = gt[win * 5 + 1];
    const float x2 = gt[win * 5 + 2];
    const float y2 = gt[win * 5 + 3];
    const int   lab = (int)gt[win * 5 + 4];

    const float dl = fmaxf(sx - x1, 0.f);
    const float dt = fmaxf(sy - y1, 0.f);
    const float dr = fmaxf(x2 - sx, 0.f);
    const float db = fmaxf(y2 - sy, 0.f);

    const float num = fminf(dl, dr) * fminf(dt, db);
    const float den = fmaxf(dl, dr) * fmaxf(dt, db);
    const float ap  = (den > 0.f) ? num / fmaxf(den, 1e-12f) : 0.0f;
    const float soft = ap * fsw[win * NLVL + lvl];

    float* crow = out_cls + (size_t)pid * (NUM_CLS + 2);
    crow[lab]          = 1.0f;
    crow[NUM_CLS]      = soft;
    crow[NUM_CLS + 1]  = 1.0f;

    const float rs = 0.25f / stride;            // exact: 1/(4*stride)
    float* rrow = out_reg + (size_t)pid * 6;
    rrow[0] = dl * rs;
    rrow[1] = dt * rs;
    rrow[2] = dr * rs;
    rrow[3] = db * rs;
    rrow[4] = soft;
    rrow[5] = 1.0f;
}

extern "C" void kernel_launch(void* const* d_in, const int* in_sizes, int n_in,
                              void* d_out, int out_size, void* d_ws, size_t ws_size,
                              hipStream_t stream) {
    (void)in_sizes; (void)n_in; (void)out_size; (void)ws_size;
    const float* gt  = (const float*)d_in[0];
    const float* fsw = (const float*)d_in[1];
    float* out_cls = (float*)d_out;
    float* out_reg = out_cls + (size_t)TOTAL_PIX * (NUM_CLS + 2);
    unsigned long long* keys = (unsigned long long*)d_ws;

    init_kernel<<<1024, 256, 0, stream>>>(out_cls, out_reg, keys);
    scatter_kernel<<<(MAX_BOXES * NLVL + 255) / 256, 256, 0, stream>>>(gt, keys);
    finalize_kernel<<<(TOTAL_PIX + 255) / 256, 256, 0, stream>>>(gt, fsw, keys,
                                                                 out_cls, out_reg);
}

// Round 4
// 71.205 us; speedup vs baseline: 1.0250x; 1.0250x over previous
//
#include <hip/hip_runtime.h>
#include <math.h>
#include <limits.h>

#define NUM_CLS   80
#define MAX_BOXES 128
#define NLVL      5
#define BIG_AREA  1.0e7f
#define TOTAL_PIX 34100
#define PPB       128          // pixels per block (2 threads per pixel)

__global__ __launch_bounds__(256) void fcos_targets_kernel(
    const float* __restrict__ gt,    // 128 x 5
    const float* __restrict__ fsw,   // 128 x 5
    float* __restrict__ out_cls,     // 34100 x 82
    float* __restrict__ out_reg)     // 34100 x 6
{
    __shared__ float4 sbx[MAX_BOXES];            // box coords x1,y1,x2,y2
    __shared__ int4   sshr[MAX_BOXES][NLVL];     // shrunk rect per (box, level)
    __shared__ float  ssw[MAX_BOXES][NLVL];      // feature_select_weight
    __shared__ int    slab[MAX_BOXES];           // labels
    __shared__ float  pbest[PPB];                // upper-half partial argmin
    __shared__ int    pwin[PPB];
    __shared__ float  st_soft[PPB];              // per-pixel staged results
    __shared__ float  st_ispos[PPB];
    __shared__ int    st_lab[PPB];
    __shared__ float  st_reg[PPB][4];

    const int t = threadIdx.x;
    const int block_base = blockIdx.x * PPB;
    const int block_last = min(block_base + PPB, TOTAL_PIX) - 1;

    // which levels does this block touch? (contiguous level ranges)
    const int lvl_lo = (block_base < 25600) ? 0 : (block_base < 32000) ? 1 :
                       (block_base < 33600) ? 2 : (block_base < 34000) ? 3 : 4;
    const int lvl_hi = (block_last < 25600) ? 0 : (block_last < 32000) ? 1 :
                       (block_last < 33600) ? 2 : (block_last < 34000) ? 3 : 4;

    // ---- phase 0: stage boxes + precompute shrink rects (only needed levels)
    if (t < MAX_BOXES) {
        const float x1 = gt[t * 5 + 0];
        const float y1 = gt[t * 5 + 1];
        const float x2 = gt[t * 5 + 2];
        const float y2 = gt[t * 5 + 3];
        sbx[t]  = make_float4(x1, y1, x2, y2);
        slab[t] = (int)gt[t * 5 + 4];
        const bool valid = (fabsf(x1) > 0.f) || (fabsf(y1) > 0.f) ||
                           (fabsf(x2) > 0.f) || (fabsf(y2) > 0.f);
        for (int l = lvl_lo; l <= lvl_hi; ++l) {
            const float inv_s = 1.0f / (float)(8 << l);   // exact pow2
            const int   fw    = 160 >> l;
            const float fwm1  = (float)(fw - 1);
            // matches reference op order exactly
            const float bx1 = x1 * inv_s, by1 = y1 * inv_s;
            const float bx2 = x2 * inv_s, by2 = y2 * inv_s;
            const float cx = (bx1 + bx2) * 0.5f;
            const float cy = (by1 + by2) * 0.5f;
            const float hw = ((bx2 - bx1) * 0.2f) * 0.5f;
            const float hh = ((by2 - by1) * 0.2f) * 0.5f;
            int px1 = (int)fminf(fmaxf(floorf(cx - hw), 0.f), fwm1);
            int py1 = (int)fminf(fmaxf(floorf(cy - hh), 0.f), fwm1);
            int px2 = min(max((int)ceilf(cx + hw), px1 + 1), fw);
            int py2 = min(max((int)ceilf(cy + hh), py1 + 1), fw);
            if (!valid) { px1 = INT_MAX; py1 = INT_MAX; px2 = 0; py2 = 0; }
            sshr[t][l] = make_int4(px1, py1, px2, py2);
        }
    } else {
        const int b = t - MAX_BOXES;
        #pragma unroll
        for (int l = 0; l < NLVL; ++l) ssw[b][l] = fsw[b * NLVL + l];
    }
    __syncthreads();

    const int count = min(PPB, TOTAL_PIX - block_base);
    const int p   = t & (PPB - 1);
    const int pid = block_base + p;
    const bool active = (p < count);

    // ---- phase 1: each half-block scans 64 boxes for its pixel
    float best = BIG_AREA;
    int   win  = (t < PPB) ? 0 : 64;
    int   lvl = 0, gx = 0, gy = 0;
    float sx = 0.f, sy = 0.f;

    if (active) {
        int fw, lp; float stride;
        if      (pid < 25600) { lvl = 0; fw = 160; lp = pid;         stride = 8.f;   }
        else if (pid < 32000) { lvl = 1; fw = 80;  lp = pid - 25600; stride = 16.f;  }
        else if (pid < 33600) { lvl = 2; fw = 40;  lp = pid - 32000; stride = 32.f;  }
        else if (pid < 34000) { lvl = 3; fw = 20;  lp = pid - 33600; stride = 64.f;  }
        else                  { lvl = 4; fw = 10;  lp = pid - 34000; stride = 128.f; }
        gy = lp / fw;
        gx = lp - gy * fw;
        sx = ((float)gx + 0.5f) * stride;
        sy = ((float)gy + 0.5f) * stride;

        const int i0 = (t < PPB) ? 0 : 64;
        for (int j = 0; j < 64; ++j) {
            const int i = i0 + j;
            const int4  s = sshr[i][lvl];
            const float4 b = sbx[i];
            const bool inb = (gx >= s.x) & (gx < s.z) & (gy >= s.y) & (gy < s.w);
            const float dl = fmaxf(sx - b.x, 0.f);
            const float dt = fmaxf(sy - b.y, 0.f);
            const float dr = fmaxf(b.z - sx, 0.f);
            const float db = fmaxf(b.w - sy, 0.f);
            const float area = inb ? (dl + dr) * (dt + db) : BIG_AREA;
            if (area < best) { best = area; win = i; }
        }
    }
    if (t >= PPB) { pbest[p] = best; pwin[p] = win; }
    __syncthreads();

    // ---- phase 2: lower half combines + epilogue + stage
    if (t < PPB && active) {
        const float b2 = pbest[p];
        if (b2 < best) { best = b2; win = pwin[p]; }   // ties keep lower index

        const int4   s = sshr[win][lvl];
        const float4 b = sbx[win];
        const bool inb = (gx >= s.x) & (gx < s.z) & (gy >= s.y) & (gy < s.w);
        const float dl = fmaxf(sx - b.x, 0.f);
        const float dt = fmaxf(sy - b.y, 0.f);
        const float dr = fmaxf(b.z - sx, 0.f);
        const float db = fmaxf(b.w - sy, 0.f);

        const float is_pos = inb ? 1.0f : 0.0f;
        const float num = fminf(dl, dr) * fminf(dt, db);
        const float den = fmaxf(dl, dr) * fmaxf(dt, db);
        const float ap  = (den > 0.f) ? num / fmaxf(den, 1e-12f) : 0.0f;
        const float soft = inb ? ap * ssw[win][lvl] : 1.0f;

        const float rs = 0.25f / (float)(8 << lvl);   // exact: 1/(4*stride)
        st_soft[p]  = soft;
        st_ispos[p] = is_pos;
        st_lab[p]   = slab[win];
        st_reg[p][0] = dl * rs * is_pos;
        st_reg[p][1] = dt * rs * is_pos;
        st_reg[p][2] = dr * rs * is_pos;
        st_reg[p][3] = db * rs * is_pos;
    }
    __syncthreads();

    // ---- phase 3: coalesced writes of the block's contiguous output region
    if (count == PPB) {
        float4* cp = (float4*)(out_cls + (size_t)block_base * (NUM_CLS + 2));
        for (int q = t; q < PPB * (NUM_CLS + 2) / 4; q += 256) {   // 2624
            const int flat = q * 4;
            const int row0 = (int)((unsigned)flat / 82u);
            const int col0 = flat - row0 * 82;
            float v[4];
            #pragma unroll
            for (int k = 0; k < 4; ++k) {
                int r = row0, c = col0 + k;
                if (c >= 82) { c -= 82; ++r; }
                const float ip = st_ispos[r];
                float val;
                if (c < NUM_CLS)       val = (c == st_lab[r] && ip != 0.f) ? 1.0f : 0.0f;
                else if (c == NUM_CLS) val = st_soft[r];
                else                   val = ip;
                v[k] = val;
            }
            cp[q] = make_float4(v[0], v[1], v[2], v[3]);
        }
        float4* rp = (float4*)(out_reg + (size_t)block_base * 6);
        for (int q = t; q < PPB * 6 / 4; q += 256) {               // 192
            const int flat = q * 4;
            const int row0 = (int)((unsigned)flat / 6u);
            const int col0 = flat - row0 * 6;
            float v[4];
            #pragma unroll
            for (int k = 0; k < 4; ++k) {
                int r = row0, c = col0 + k;
                if (c >= 6) { c -= 6; ++r; }
                v[k] = (c < 4) ? st_reg[r][c] : ((c == 4) ? st_soft[r] : st_ispos[r]);
            }
            rp[q] = make_float4(v[0], v[1], v[2], v[3]);
        }
    } else {
        // edge block: scalar guarded writes
        float* cbase = out_cls + (size_t)block_base * (NUM_CLS + 2);
        for (int q = t; q < count * (NUM_CLS + 2); q += 256) {
            const int r = (int)((unsigned)q / 82u);
            const int c = q - r * 82;
            const float ip = st_ispos[r];
            float val;
            if (c < NUM_CLS)       val = (c == st_lab[r] && ip != 0.f) ? 1.0f : 0.0f;
            else if (c == NUM_CLS) val = st_soft[r];
            else                   val = ip;
            cbase[q] = val;
        }
        float* rbase = out_reg + (size_t)block_base * 6;
        for (int q = t; q < count * 6; q += 256) {
            const int r = (int)((unsigned)q / 6u);
            const int c = q - r * 6;
            rbase[q] = (c < 4) ? st_reg[r][c] : ((c == 4) ? st_soft[r] : st_ispos[r]);
        }
    }
}

extern "C" void kernel_launch(void* const* d_in, const int* in_sizes, int n_in,
                              void* d_out, int out_size, void* d_ws, size_t ws_size,
                              hipStream_t stream) {
    (void)in_sizes; (void)n_in; (void)out_size; (void)d_ws; (void)ws_size;
    const float* gt  = (const float*)d_in[0];
    const float* fsw = (const float*)d_in[1];
    float* out_cls = (float*)d_out;
    float* out_reg = out_cls + (size_t)TOTAL_PIX * (NUM_CLS + 2);

    const int blocks = (TOTAL_PIX + PPB - 1) / PPB;   // 267
    fcos_targets_kernel<<<blocks, 256, 0, stream>>>(gt, fsw, out_cls, out_reg);
}